// Round 8
// baseline (727.204 us; speedup 1.0000x reference)
//
#include <hip/hip_runtime.h>
#include <cstdint>

#define NN 20000     // nodes
#define NE 640000    // edges
#define NB 128       // basis
#define NG 64        // gaussians
#define NH 256       // hidden
#define NT_MAX 58752 // padded 16-edge tiles: sum ceil(cnt/16) <= (NE+15*NN)/16 = 58750; 58752 = 16*3672 = 32*1836

typedef __attribute__((ext_vector_type(8))) _Float16 h16x8;
typedef __attribute__((ext_vector_type(4))) float f32x4;
typedef __attribute__((ext_vector_type(4))) float fvec4;
typedef __attribute__((ext_vector_type(4))) unsigned uvec4;

// pack two f32 -> packed fp16 dword, round-toward-zero (1 instr): low half = a
__device__ __forceinline__ unsigned pkh(float a, float b){
  auto t = __builtin_amdgcn_cvt_pkrtz(a, b);
  return __builtin_bit_cast(unsigned, t);
}
// pack two f32 -> packed fp16 dword, RNE (for weights; one-time cost)
__device__ __forceinline__ unsigned pkh_rne(float a, float b){
  union{ _Float16 h[2]; unsigned u; } v;
  v.h[0] = (_Float16)a; v.h[1] = (_Float16)b; return v.u;
}
// packed fp16 pair * packed fp16 pair -> packed fp16 products (1 instr)
__device__ __forceinline__ unsigned pkmul(unsigned a, unsigned b){
  unsigned r; asm("v_pk_mul_f16 %0, %1, %2" : "=v"(r) : "v"(a), "v"(b)); return r;
}
__device__ __forceinline__ short f2h(float f){
  union{ _Float16 h[2]; short s[2]; } v; v.h[0] = (_Float16)f; return v.s[0];
}

__device__ __forceinline__ float tanh_fast(float x){
  float t = __builtin_amdgcn_exp2f(x * 2.8853900817779268f);
  return __builtin_fmaf(-2.f, __builtin_amdgcn_rcpf(t + 1.f), 1.f);
}

// async global->LDS DMA, 16B per lane, dest = uniform base + lane*16 (HW)
__device__ __forceinline__ void load_lds16(const void* g, void* l){
  __builtin_amdgcn_global_load_lds(
    (const __attribute__((address_space(1))) unsigned*)g,
    (__attribute__((address_space(3))) unsigned*)l, 16, 0, 0);
}

// Stage W[N=NT*16][K=KT*32] (f32) as fp16 MFMA B-fragments into LDS.
template<int NT, int KT>
__device__ __forceinline__ void stage_w(const float* __restrict__ W, short* lds){
  const int total = NT*KT*64;
  for(int c = (int)threadIdx.x; c < total; c += 256){
    int lane = c & 63;
    int kt = (c >> 6) % KT;
    int n  = c / (64*KT);
    int row = n*16 + (lane & 15);
    int col = kt*32 + (lane >> 4)*8;
    const float* p = W + (size_t)row*(KT*32) + col;
    unsigned* d = (unsigned*)(lds + (size_t)c*8);
#pragma unroll
    for(int j=0;j<4;j++) d[j] = pkh_rne(p[2*j], p[2*j+1]);
  }
}

// ---------------- fused embed + dst histogram ----------------
__global__ void k_prep0(const int* __restrict__ Z, const float* __restrict__ E,
                        float* __restrict__ C, const int* __restrict__ dst, int* __restrict__ cnt){
  int i = blockIdx.x*256 + threadIdx.x;    // exactly NN*32 == NE == 640000
  int node = i >> 5, k4 = i & 31;
  ((float4*)C)[i] = ((const float4*)(E + (size_t)Z[node]*NB))[k4];
  atomicAdd(&cnt[dst[i]], 1);
}

// ---------------- padded-tile scan ----------------
// ptstart[v] = prefix of ceil(cnt[v]/16) (tile units), ptstart[NN] = total.
// cursor[v] = ptstart[v]*16 (edge-slot base for k_fill).
// tnode[t] = owner node of tile t (tail stays -1 from memset).
__global__ __launch_bounds__(1024) void k_scan(const int* __restrict__ cnt, int* __restrict__ ptstart,
                                               int* __restrict__ cursor, int* __restrict__ tnode){
  __shared__ int lds[1024];
  const int t = threadIdx.x;
  const int base = t*20;
  int4 v[5];
  if(base + 19 < NN){
#pragma unroll
    for(int j=0;j<5;j++) v[j] = ((const int4*)(cnt + base))[j];
  } else {
#pragma unroll
    for(int j=0;j<5;j++) v[j] = make_int4(0,0,0,0);
  }
  const int* ve = (const int*)v;
  int loc[20], tl[20]; int s = 0;
#pragma unroll
  for(int j=0;j<20;j++){
    int c = ve[j];
    int ti = (c + 15) >> 4;
    loc[j] = s; tl[j] = ti; s += ti;
  }
  lds[t] = s;
  __syncthreads();
  for(int off=1; off<1024; off<<=1){
    int x = (t >= off) ? lds[t-off] : 0;
    __syncthreads();
    lds[t] += x;
    __syncthreads();
  }
  int prefix = (t > 0) ? lds[t-1] : 0;
#pragma unroll
  for(int j=0;j<20;j++){
    int i = base+j;
    if(i < NN){
      int pt = prefix + loc[j];
      ptstart[i] = pt;
      cursor[i]  = pt << 4;
      for(int k=0;k<tl[j];k++) tnode[pt+k] = i;
    }
  }
  if(t == 999) ptstart[NN] = lds[999];   // NN = 1000*20: thread 999 ends the real range
}

__global__ void k_fill(const int* __restrict__ src, const int* __restrict__ dst,
                       int* __restrict__ cur, int* __restrict__ perm,
                       int* __restrict__ srcv){
  int e = blockIdx.x*256 + threadIdx.x;
  if(e < NE){
    int v = dst[e];
    int p = atomicAdd(&cur[v], 1);
    perm[p] = e;
    srcv[p] = src[e];
  }
}

// ---------------- d_feat = edge_attr[perm] @ dfW.T + dfb ----------------
// fp16, PADDED slot order, MFMA-fragment layout: tile16*2048 + kt*512 + lane*8.
// Padding slots (perm = -1) write EXACT ZEROS (validity mask) so k_edge's
// padded rows contribute tanh(0)=0 with no masking there.
#define TPAD 136
__global__ __launch_bounds__(256,3) void k_dprep(
  const float* __restrict__ ea, const int* __restrict__ perm, const int* __restrict__ tnode,
  const float* __restrict__ dfW, const float* __restrict__ dfb, short* __restrict__ dft)
{
  __shared__ short ldsW[8*2*64*8];     // 16 KB
  __shared__ short ldsT[4*32*TPAD];    // 34816 B
  stage_w<8,2>(dfW, ldsW);
  __syncthreads();
  const int lane = threadIdx.x & 63, wave = threadIdx.x >> 6;
  const int quad = lane>>4, lc = lane&15;
  short* myT = ldsT + wave*32*TPAD;
  const int wid = blockIdx.x*4 + wave;        // 3672*4 = 14688 waves, 4 tiles each = 58752
  if(tnode[wid*4] < 0) return;                // whole range is tail (tnode monotone)
  const int chunkA = wid*2, chunkB = wid*2+1; // 32-slot chunks

  float bias[8];
#pragma unroll
  for(int n2=0;n2<8;n2++) bias[n2] = dfb[n2*16 + lc];

  int pA[2], pB[2];
#pragma unroll
  for(int mt=0;mt<2;mt++){
    pA[mt] = perm[(size_t)chunkA*32 + mt*16 + lc];
    pB[mt] = perm[(size_t)chunkB*32 + mt*16 + lc];
  }
  unsigned mAs[2], mBs[2];
#pragma unroll
  for(int mt=0;mt<2;mt++){
    mAs[mt] = (unsigned)__ballot(pA[mt] >= 0) & 0xFFFFu;
    mBs[mt] = (unsigned)__ballot(pB[mt] >= 0) & 0xFFFFu;
  }

  // raw ea gathers, chunk A (padding rows read ea[0] -- finite, zeroed on store)
  fvec4 rA[2][2][2];
#pragma unroll
  for(int mt=0;mt<2;mt++){
    int e = pA[mt] < 0 ? 0 : pA[mt];
    const float* p = ea + (size_t)e*NG;
#pragma unroll
    for(int kt=0;kt<2;kt++){
      const float* q = p + kt*32 + quad*8;
      rA[mt][kt][0] = __builtin_nontemporal_load((const fvec4*)q);
      rA[mt][kt][1] = __builtin_nontemporal_load((const fvec4*)(q+4));
    }
  }

  f32x4 z = {0.f,0.f,0.f,0.f};

  auto convert_mfma = [&](fvec4 (&raw)[2][2][2], f32x4 (&acc)[2][8]){
#pragma unroll
    for(int mt=0;mt<2;mt++)
#pragma unroll
      for(int n2=0;n2<8;n2++) acc[mt][n2] = z;
#pragma unroll
    for(int kt=0;kt<2;kt++){
      h16x8 a0, a1;
      {
        union{ h16x8 v; unsigned u[4]; } t0, t1;
        fvec4 c0 = raw[0][kt][0], c1 = raw[0][kt][1];
        fvec4 d0 = raw[1][kt][0], d1 = raw[1][kt][1];
        t0.u[0]=pkh(c0.x,c0.y); t0.u[1]=pkh(c0.z,c0.w); t0.u[2]=pkh(c1.x,c1.y); t0.u[3]=pkh(c1.z,c1.w);
        t1.u[0]=pkh(d0.x,d0.y); t1.u[1]=pkh(d0.z,d0.w); t1.u[2]=pkh(d1.x,d1.y); t1.u[3]=pkh(d1.z,d1.w);
        a0 = t0.v; a1 = t1.v;
      }
#pragma unroll
      for(int n2=0;n2<8;n2++){
        h16x8 b = *(const h16x8*)(ldsW + ((size_t)(n2*2+kt)*64 + lane)*8);
        acc[0][n2] = __builtin_amdgcn_mfma_f32_16x16x32_f16(a0, b, acc[0][n2], 0, 0, 0);
        acc[1][n2] = __builtin_amdgcn_mfma_f32_16x16x32_f16(a1, b, acc[1][n2], 0, 0, 0);
      }
    }
  };

  auto store_tile = [&](f32x4 (&acc)[2][8], int chunk, unsigned* msk){
#pragma unroll
    for(int n2=0;n2<8;n2++)
#pragma unroll
      for(int mt=0;mt<2;mt++)
#pragma unroll
        for(int r=0;r<4;r++){
          float sel = (float)((msk[mt] >> (quad*4 + r)) & 1u);
          myT[(mt*16 + quad*4 + r)*TPAD + n2*16 + lc] = f2h((acc[mt][n2][r] + bias[n2])*sel);
        }
    short* gout = dft + (size_t)chunk*4096;
#pragma unroll
    for(int s16=0;s16<2;s16++)
#pragma unroll
      for(int kt=0;kt<4;kt++){
        uvec4 vv = *(const uvec4*)(myT + (size_t)(s16*16 + lc)*TPAD + kt*32 + quad*8);
        __builtin_nontemporal_store(vv, (uvec4*)(gout + s16*2048 + kt*512 + lane*8));
      }
  };

  f32x4 accA[2][8];
  convert_mfma(rA, accA);

  fvec4 rB[2][2][2];
#pragma unroll
  for(int mt=0;mt<2;mt++){
    int e = pB[mt] < 0 ? 0 : pB[mt];
    const float* p = ea + (size_t)e*NG;
#pragma unroll
    for(int kt=0;kt<2;kt++){
      const float* q = p + kt*32 + quad*8;
      rB[mt][kt][0] = __builtin_nontemporal_load((const fvec4*)q);
      rB[mt][kt][1] = __builtin_nontemporal_load((const fvec4*)(q+4));
    }
  }

  store_tile(accA, chunkA, mAs);

  f32x4 accB[2][8];
  convert_mfma(rB, accB);
  store_tile(accB, chunkB, mBs);
}

// ---------------- cfC = fp16(C @ cfW.T + cfb) on nodes, LDS-transposed stores ----------------
__global__ __launch_bounds__(256,3) void k_cf(
  const float* __restrict__ C, const float* __restrict__ cfW,
  const float* __restrict__ cfb, short* __restrict__ cfC)
{
  __shared__ short ldsW[8*4*64*8];     // 32 KB
  __shared__ short ldsT[4*16*TPAD];    // 17408 B
  stage_w<8,4>(cfW, ldsW);
  __syncthreads();
  const int lane = threadIdx.x & 63, wave = threadIdx.x >> 6;
  const int quad = lane>>4, lc = lane&15;
  short* myT = ldsT + wave*16*TPAD;
  const int tile = blockIdx.x*4 + wave;       // 313*4 = 1252 >= 1250 tiles
  if(tile >= NN/16) return;
  const int base = tile*16;
  h16x8 a[4];
  const float* p = C + (size_t)(base + lc)*NB;
#pragma unroll
  for(int kt=0;kt<4;kt++){
    const float* q = p + kt*32 + quad*8;
    float4 c0 = *(const float4*)q, c1 = *(const float4*)(q+4);
    union{ h16x8 v; unsigned u[4]; } t;
    t.u[0]=pkh(c0.x,c0.y); t.u[1]=pkh(c0.z,c0.w); t.u[2]=pkh(c1.x,c1.y); t.u[3]=pkh(c1.z,c1.w);
    a[kt] = t.v;
  }
  f32x4 acc[8];
  f32x4 z = {0.f,0.f,0.f,0.f};
#pragma unroll
  for(int n2=0;n2<8;n2++) acc[n2] = z;
#pragma unroll
  for(int kt=0;kt<4;kt++)
#pragma unroll
    for(int n2=0;n2<8;n2++){
      h16x8 b = *(const h16x8*)(ldsW + ((size_t)(n2*4+kt)*64 + lane)*8);
      acc[n2] = __builtin_amdgcn_mfma_f32_16x16x32_f16(a[kt], b, acc[n2], 0, 0, 0);
    }
#pragma unroll
  for(int n2=0;n2<8;n2++){
    float bias = cfb[n2*16 + lc];
#pragma unroll
    for(int r=0;r<4;r++)
      myT[(quad*4 + r)*TPAD + n2*16 + lc] = f2h(acc[n2][r] + bias);
  }
  short* gout = cfC + (size_t)base*NB;
#pragma unroll
  for(int i=0;i<4;i++){
    int s_ = i*512 + lane*8;
    int row = s_ >> 7, col = s_ & 127;
    uint4 vv = *(const uint4*)(myT + row*TPAD + col);
    *(uint4*)(gout + s_) = vv;
  }
}

// ---------------- edge kernel v4: node-aligned tiles, NO atomics, per-tile partials ----------------
// Every 16-edge tile belongs to exactly one node (padding). Per tile: DMA-stage
// dft, gather cfC, pkmul+MFMA, tanh, FULL-tile column sum (no segments), 2 plain
// stores to partial[tile][128]. Fixed instruction count -> static counted vmcnt.
// Ledger (outstanding oldest->newest entering wait at iter t, steady state):
//   [st(t-1) x2, S(t) x4, C(t) x4, S(t+1) x4] = 14 -> vmcnt(6) retains
//   {st(t-1) x2? NO: completes st(t-1),S(t),C(t); retains S(t+1) x4 + ...}
//   -- verified: needs {S(t), C(t)} complete before compute, holds at every t.
#define TPW 8
__global__ __launch_bounds__(256,2) void k_edge(
    const short* __restrict__ cfC, const short* __restrict__ dft,
    const int* __restrict__ srcv, const int* __restrict__ tnode,
    const float* __restrict__ fcW, float* __restrict__ partial)
{
  __shared__ short ldsW[8*4*64*8];   // 32 KB
  __shared__ short ldsD[4*2*2048];   // 32 KB: 4 waves x 2 bufs x 4KB
  stage_w<8,4>(fcW, ldsW);
  __syncthreads();
  const int lane = threadIdx.x & 63, wave = threadIdx.x >> 6;
  const int quad = lane>>4, lc = lane&15;
  const int wid = blockIdx.x*4 + wave;        // 1836*4 = 7344 waves x 8 tiles = 58752
  const int tile0 = wid*TPW;
  if(tnode[tile0] < 0) return;                // pure-tail wave (tnode monotone)
  short* dbuf = ldsD + wave*4096;

  auto stage = [&](int t16, int b){
    const char* g = (const char*)(dft + (size_t)t16*2048);
    short* d = dbuf + b*2048;
#pragma unroll
    for(int j=0;j<4;j++) load_lds16(g + j*1024 + (size_t)lane*16, d + j*512);
  };

  // prologue: all src indices up front (static), first stage, first cc
  int sv[TPW];
#pragma unroll
  for(int t=0;t<TPW;t++) sv[t] = srcv[(size_t)(tile0+t)*16 + lc];
  stage(tile0, 0);
  uint4 cc[2][4];
  {
    const short* cp = cfC + (size_t)sv[0]*NB;
#pragma unroll
    for(int kt=0;kt<4;kt++) cc[0][kt] = *(const uint4*)(cp + kt*32 + quad*8);
  }

#pragma unroll
  for(int t=0; t<TPW; t++){
    const int cur = t & 1, nxt = cur ^ 1;

    if(t+1 < TPW) stage(tile0 + t + 1, nxt);

    // counted wait: drain stage(t)+cc(t); keep {stores(t-1), stage(t+1)}
    if(t == 0)          { asm volatile("s_waitcnt vmcnt(4)" ::: "memory"); }
    else if(t < TPW-1)  { asm volatile("s_waitcnt vmcnt(6)" ::: "memory"); }
    else                { asm volatile("s_waitcnt vmcnt(2)" ::: "memory"); }
    __builtin_amdgcn_sched_barrier(0);

    if(t+1 < TPW){
      const short* cp = cfC + (size_t)sv[t+1]*NB;
#pragma unroll
      for(int kt=0;kt<4;kt++) cc[nxt][kt] = *(const uint4*)(cp + kt*32 + quad*8);
    }

    f32x4 acc[8];
    f32x4 z = {0.f,0.f,0.f,0.f};
#pragma unroll
    for(int n2=0;n2<8;n2++) acc[n2] = z;
#pragma unroll
    for(int kt=0;kt<4;kt++){
      h16x8 a;
      {
        union{ h16x8 v; unsigned u[4]; } dv_, t0;
        dv_.v = *(const h16x8*)(dbuf + cur*2048 + kt*512 + lane*8);
        uint4 c0 = cc[cur][kt];
        t0.u[0] = pkmul(c0.x, dv_.u[0]); t0.u[1] = pkmul(c0.y, dv_.u[1]);
        t0.u[2] = pkmul(c0.z, dv_.u[2]); t0.u[3] = pkmul(c0.w, dv_.u[3]);
        a = t0.v;
      }
#pragma unroll
      for(int n2=0;n2<8;n2++){
        h16x8 b = *(const h16x8*)(ldsW + ((size_t)(n2*4 + kt)*64 + lane)*8);
        acc[n2] = __builtin_amdgcn_mfma_f32_16x16x32_f16(a, b, acc[n2], 0, 0, 0);
      }
    }

    // tanh + full-tile column sum (padding rows are exactly 0 -> tanh 0)
    float sums[8];
#pragma unroll
    for(int n2=0;n2<8;n2++){
      float s01 = tanh_fast(acc[n2][0]) + tanh_fast(acc[n2][1]);
      float s23 = tanh_fast(acc[n2][2]) + tanh_fast(acc[n2][3]);
      sums[n2] = s01 + s23;
    }
#pragma unroll
    for(int n2=0;n2<8;n2++){
      sums[n2] += __shfl_xor(sums[n2], 16);
      sums[n2] += __shfl_xor(sums[n2], 32);
    }
    const int n2w = quad*2;
    float* po = partial + (size_t)(tile0 + t)*NB;
    po[n2w*16 + lc]     = sums[n2w];
    po[(n2w+1)*16 + lc] = sums[n2w+1];
  }
}

// ---------------- aggregate per-tile partials into C (no atomics: node-owned) ----------------
__global__ void k_agg(const float* __restrict__ partial, const int* __restrict__ ptstart,
                      float* __restrict__ C){
  int g = blockIdx.x*256 + threadIdx.x;   // NN*32 = 640000 threads (float4 per thread)
  int v = g >> 5, c = g & 31;
  int t0 = ptstart[v], t1 = ptstart[v+1];
  const float4* P = (const float4*)partial;
  float4 a = ((const float4*)C)[(size_t)v*32 + c];
  for(int t=t0; t<t1; t++){
    float4 p = P[(size_t)t*32 + c];
    a.x += p.x; a.y += p.y; a.z += p.z; a.w += p.w;
  }
  ((float4*)C)[(size_t)v*32 + c] = a;
}

// ---------------- readout: out += pool(tanh(C@r1W.T + r1b)@r2W.T + r2b) ----------------
__global__ __launch_bounds__(256,2) void k_readout(
  const float* __restrict__ C, const float* __restrict__ r1W, const float* __restrict__ r1b,
  const float* __restrict__ r2W, const float* __restrict__ r2b,
  const int* __restrict__ batch, float* __restrict__ out)
{
  __shared__ short ldsW[16*4*64*8];  // 64 KB
  stage_w<16,4>(r1W, ldsW);
  __syncthreads();
  const int lane = threadIdx.x & 63, wave = threadIdx.x >> 6;
  const int quad = lane>>4, lc = lane&15;
  const int base = (blockIdx.x*4 + wave)*16;
  if(base >= NN) return;
  int node = base + lc; if(node > NN-1) node = NN-1;
  h16x8 a[4];
  const float* p = C + (size_t)node*NB;
#pragma unroll
  for(int kt=0;kt<4;kt++){
    const float* q = p + kt*32 + quad*8;
    float4 c0 = *(const float4*)q, c1 = *(const float4*)(q+4);
    union{ h16x8 v; unsigned u[4]; } t;
    t.u[0]=pkh(c0.x,c0.y); t.u[1]=pkh(c0.z,c0.w); t.u[2]=pkh(c1.x,c1.y); t.u[3]=pkh(c1.z,c1.w);
    a[kt] = t.v;
  }
  f32x4 acc[16];
  f32x4 z = {0.f,0.f,0.f,0.f};
#pragma unroll
  for(int nt=0;nt<16;nt++) acc[nt] = z;
#pragma unroll
  for(int kt=0;kt<4;kt++)
#pragma unroll
    for(int nt=0;nt<16;nt++){
      h16x8 b = *(const h16x8*)(ldsW + ((size_t)(nt*4+kt)*64 + lane)*8);
      acc[nt] = __builtin_amdgcn_mfma_f32_16x16x32_f16(a[kt], b, acc[nt], 0, 0, 0);
    }
#pragma unroll
  for(int nt=0;nt<16;nt++){
    float bias = r1b[nt*16 + lc];
#pragma unroll
    for(int r=0;r<4;r++) acc[nt][r] = tanh_fast(acc[nt][r] + bias);
  }
#pragma unroll
  for(int r=0;r<4;r++){
    int nd = base + quad*4 + r;
#pragma unroll
    for(int o=0;o<4;o++){
      float ps = 0.f;
#pragma unroll
      for(int nt=0;nt<16;nt++) ps = __builtin_fmaf(acc[nt][r], r2W[(size_t)o*NH + nt*16 + lc], ps);
      ps += __shfl_xor(ps, 1);
      ps += __shfl_xor(ps, 2);
      ps += __shfl_xor(ps, 4);
      ps += __shfl_xor(ps, 8);
      if(lc == 0 && nd < NN) atomicAdd(&out[batch[nd]*4 + o], ps + r2b[o]);
    }
  }
}

extern "C" void kernel_launch(void* const* d_in, const int* in_sizes, int n_in,
                              void* d_out, int out_size, void* d_ws, size_t ws_size,
                              hipStream_t stream) {
  const int*   Z      = (const int*)d_in[0];
  const int*   ei     = (const int*)d_in[1];
  const float* ea     = (const float*)d_in[2];
  const int*   batch  = (const int*)d_in[3];
  const float* embedW = (const float*)d_in[4];
  const float* cfW    = (const float*)d_in[5];
  const float* cfb    = (const float*)d_in[6];
  const float* dfW    = (const float*)d_in[7];
  const float* dfb    = (const float*)d_in[8];
  const float* fcW    = (const float*)d_in[9];
  const float* r1W    = (const float*)d_in[10];
  const float* r1b    = (const float*)d_in[11];
  const float* r2W    = (const float*)d_in[12];
  const float* r2b    = (const float*)d_in[13];
  const int* src = ei;
  const int* dst = ei + NE;

  char* p = (char*)d_ws;
  auto alloc = [&](size_t b){ char* r = p; p += (b + 255) & ~(size_t)255; return r; };
  float* CA     = (float*)alloc((size_t)NN*NB*4);
  short* cfC    = (short*)alloc((size_t)NN*NB*2);
  short* dft    = (short*)alloc((size_t)NT_MAX*2048*2);   // padded, fragment order
  float* partial= (float*)alloc((size_t)NT_MAX*NB*4);
  int*   cnt    = (int*)alloc((size_t)NN*4);
  int*   ptstart= (int*)alloc((size_t)(NN+1)*4);
  int*   cursor = (int*)alloc((size_t)NN*4);
  int*   perm   = (int*)alloc((size_t)NT_MAX*16*4);
  int*   srcv   = (int*)alloc((size_t)NT_MAX*16*4);
  int*   tnode  = (int*)alloc((size_t)NT_MAX*4);
  size_t needed = (size_t)(p - (char*)d_ws);

  (void)hipMemsetAsync(d_out, 0, (size_t)out_size*sizeof(float), stream);
  if(needed > ws_size) return;   // all-zero output = ws-too-small diagnostic

  (void)hipMemsetAsync(cnt,   0,    (size_t)NN*4, stream);
  (void)hipMemsetAsync(perm,  0xFF, (size_t)NT_MAX*16*4, stream);  // -1 = padding
  (void)hipMemsetAsync(srcv,  0,    (size_t)NT_MAX*16*4, stream);  // padding src = node 0
  (void)hipMemsetAsync(tnode, 0xFF, (size_t)NT_MAX*4, stream);     // -1 = tail tile

  k_prep0<<<2500, 256, 0, stream>>>(Z, embedW, CA, dst, cnt);
  k_scan <<<1,   1024, 0, stream>>>(cnt, ptstart, cursor, tnode);
  k_fill <<<2500, 256, 0, stream>>>(src, dst, cursor, perm, srcv);
  k_dprep<<<3672, 256, 0, stream>>>(ea, perm, tnode, dfW, dfb, dft);

  for(int it = 0; it < 3; it++){
    k_cf  <<<313,  256, 0, stream>>>(CA, cfW, cfb, cfC);
    k_edge<<<1836, 256, 0, stream>>>(cfC, dft, srcv, tnode, fcW, partial);
    k_agg <<<2500, 256, 0, stream>>>(partial, ptstart, CA);
  }
  k_readout<<<313, 256, 0, stream>>>(CA, r1W, r1b, r2W, r2b, batch, (float*)d_out);
}